// Round 7
// baseline (303.206 us; speedup 1.0000x reference)
//
#include <hip/hip_runtime.h>
#include <hip/hip_bf16.h>
#include <math.h>

#define NB 4
#define NN 1024
#define DIMD 512
#define NH 8
#define DHD 64
#define INNERD 512
#define SCALE 0.125f
#define TEMPP 0.1f
#define KREG 0.3f
#define LNEG -23.025850929940457f

typedef __attribute__((ext_vector_type(8))) short bf16x8;
typedef __attribute__((ext_vector_type(4))) short bf16x4;
typedef __attribute__((ext_vector_type(4))) float f32x4;

static __device__ __forceinline__ short f2bf(float f) {
  unsigned u = __float_as_uint(f);
  u += 0x7fffu + ((u >> 16) & 1u);
  return (short)(u >> 16);
}
static __device__ __forceinline__ float bf2f(short s) {
  unsigned u = ((unsigned)(unsigned short)s) << 16;
  return __uint_as_float(u);
}

static __device__ __forceinline__ float wave_sum(float v) {
#pragma unroll
  for (int o = 1; o < 64; o <<= 1) v += __shfl_xor(v, o, 64);
  return v;
}
static __device__ __forceinline__ float wave_min(float v) {
#pragma unroll
  for (int o = 1; o < 64; o <<= 1) v = fminf(v, __shfl_xor(v, o, 64));
  return v;
}

// ---------------------------------------------------------------------------
// K1: fused QKV projection. out = x @ W.T + b, written bf16 in (B,H,N,DH).
// qn stores 1/(||q||*TEMP), kn stores 1/||k||. grid (64, 24)
// ---------------------------------------------------------------------------
__global__ __launch_bounds__(256) void k_qkv(
    const float* __restrict__ x,
    const float* __restrict__ Wq, const float* __restrict__ bq,
    const float* __restrict__ Wk, const float* __restrict__ bk,
    const float* __restrict__ Wv, const float* __restrict__ bv,
    short* __restrict__ Qb, short* __restrict__ Kb, short* __restrict__ Vb,
    float* __restrict__ qn, float* __restrict__ kn) {
  __shared__ __align__(16) short As[64][40];
  __shared__ __align__(16) short Bs[64][40];
  const int tid = threadIdx.x;
  const int lane = tid & 63;
  const int wv = tid >> 6;
  const int m0 = blockIdx.x * 64;
  const int oc = blockIdx.y;
  const int which = oc >> 3;  // 0=q 1=k 2=v
  const int h = oc & 7;
  const float* W = (which == 0) ? Wq : (which == 1) ? Wk : Wv;
  const float* bias = (which == 0) ? bq : (which == 1) ? bk : bv;
  short* Out = (which == 0) ? Qb : (which == 1) ? Kb : Vb;
  const int o0 = h * 64;

  const f32x4 zero4 = {0.f, 0.f, 0.f, 0.f};
  f32x4 acc[4] = {zero4, zero4, zero4, zero4};

  const int sr = tid >> 3;
  const int sc = (tid & 7) * 4;

  for (int ks = 0; ks < 16; ++ks) {
    const int k0 = ks * 32;
    __syncthreads();
#pragma unroll
    for (int t = 0; t < 2; ++t) {
      const int r = sr + t * 32;
      const f32x4 va = *reinterpret_cast<const f32x4*>(&x[(m0 + r) * DIMD + k0 + sc]);
      const f32x4 vb = *reinterpret_cast<const f32x4*>(&W[(o0 + r) * DIMD + k0 + sc]);
      bf16x4 pa, pb;
#pragma unroll
      for (int i2 = 0; i2 < 4; ++i2) { pa[i2] = f2bf(va[i2]); pb[i2] = f2bf(vb[i2]); }
      *reinterpret_cast<bf16x4*>(&As[r][sc]) = pa;
      *reinterpret_cast<bf16x4*>(&Bs[r][sc]) = pb;
    }
    __syncthreads();
    const int kk = (lane >> 4) * 8;
    const bf16x8 a = *reinterpret_cast<const bf16x8*>(&As[wv * 16 + (lane & 15)][kk]);
#pragma unroll
    for (int n = 0; n < 4; ++n) {
      const bf16x8 b = *reinterpret_cast<const bf16x8*>(&Bs[n * 16 + (lane & 15)][kk]);
      acc[n] = __builtin_amdgcn_mfma_f32_16x16x32_bf16(a, b, acc[n], 0, 0, 0);
    }
  }

  const int colb = lane & 15;
  const int rbase = m0 + wv * 16 + ((lane >> 4) << 2);
  const int bidx = m0 >> 10;
  const int hb = (bidx * NH + h) << 10;
  float p2[4] = {0.f, 0.f, 0.f, 0.f};
#pragma unroll
  for (int n = 0; n < 4; ++n) {
    const float bval = bias[o0 + n * 16 + colb];
#pragma unroll
    for (int i = 0; i < 4; ++i) {
      const float val = acc[n][i] + bval;
      p2[i] += val * val;
      const int m = rbase + i;
      Out[(long)(hb + (m & (NN - 1))) * DHD + n * 16 + colb] = f2bf(val);
    }
  }
  if (which < 2) {
    float* norm = (which == 0) ? qn : kn;
#pragma unroll
    for (int off = 1; off < 16; off <<= 1) {
#pragma unroll
      for (int i = 0; i < 4; ++i) p2[i] += __shfl_xor(p2[i], off, 64);
    }
    if (colb == 0) {
#pragma unroll
      for (int i = 0; i < 4; ++i) {
        const int m = rbase + i;
        const float nv = sqrtf(p2[i]);
        norm[hb + (m & (NN - 1))] = (which == 0) ? (1.0f / (nv * TEMPP)) : (1.0f / nv);
      }
    }
  }
}

// ---------------------------------------------------------------------------
// K1.5: transpose V: (bh, j, d) -> (bh, d, j). grid (16, 32)
// ---------------------------------------------------------------------------
__global__ __launch_bounds__(256) void k_vtrans(const short* __restrict__ Vb,
                                                short* __restrict__ VbT) {
  __shared__ __align__(16) short T[64][72];
  const int tid = threadIdx.x;
  const int bh = blockIdx.y;
  const int j0 = blockIdx.x * 64;
#pragma unroll
  for (int t = 0; t < 2; ++t) {
    const int idx = tid + 256 * t;
    const int r = idx >> 3, c8 = (idx & 7) * 8;
    *reinterpret_cast<bf16x8*>(&T[r][c8]) =
        *reinterpret_cast<const bf16x8*>(&Vb[(long)((bh << 10) + j0 + r) * DHD + c8]);
  }
  __syncthreads();
  const int d = tid & 63;
  const int cg = tid >> 6;
#pragma unroll
  for (int t = 0; t < 2; ++t) {
    const int ch = cg * 2 + t;
    bf16x8 v;
#pragma unroll
    for (int jj = 0; jj < 8; ++jj) v[jj] = T[ch * 8 + jj][d];
    *reinterpret_cast<bf16x8*>(&VbT[((long)(bh * DHD + d) << 10) + j0 + ch * 8]) = v;
  }
}

// ---------------------------------------------------------------------------
// K2: per-(b,h) softmax bound: kms[bh] = max_j ||k_j|| * SCALE / TEMP.
// kn holds 1/||k|| -> max||k|| = 1/min(kn). grid (32), 256 threads.
// ---------------------------------------------------------------------------
__global__ __launch_bounds__(256) void k_kmax(const float* __restrict__ kn,
                                              float* __restrict__ kms) {
  const int tid = threadIdx.x;
  const int bh = blockIdx.x;
  const f32x4 v = *reinterpret_cast<const f32x4*>(&kn[(bh << 10) + tid * 4]);
  float m = fminf(fminf(v[0], v[1]), fminf(v[2], v[3]));
  m = wave_min(m);
  __shared__ float red[4];
  if ((tid & 63) == 0) red[tid >> 6] = m;
  __syncthreads();
  if (tid == 0) {
    const float mn = fminf(fminf(red[0], red[1]), fminf(red[2], red[3]));
    kms[bh] = (1.0f / mn) * SCALE / TEMPP;
  }
}

// swizzled LDS accessor: row stride 2048 B, XOR bits 4..6 with (r&7)
static __device__ __forceinline__ short* sp(short* S, int r, int c) {
  return (short*)((char*)S + (((r << 11) + (c << 1)) ^ ((r & 7) << 4)));
}

// ---------------------------------------------------------------------------
// K3: FUSED scores + STREAMING softmax (swapped-operand QK^T: lane holds
// 4 consecutive j for one q-row -> mask/kn are f32x4 loads, exp overlaps
// MFMA, no barrier in the main loop) + dcl stats + popcount + PV.
// Block = 16 query rows of one (b,h). grid (64, 32), 256 threads.
// ---------------------------------------------------------------------------
__global__ __launch_bounds__(256) void k_attn(
    const short* __restrict__ Qb, const short* __restrict__ Kb,
    const short* __restrict__ VbT,
    const float* __restrict__ mask,
    const float* __restrict__ qn, const float* __restrict__ kn,
    const float* __restrict__ kms,
    float* __restrict__ attn, short* __restrict__ AVb,
    float* __restrict__ partial, float* __restrict__ partial2) {
  __shared__ short S[16 * 1024];   // bf16 ev (unnormalized P), swizzled
  __shared__ float red[4][16][3];  // per-wave per-q partials: Z, alls, pos
  __shared__ float redc[4][16];    // per-wave per-q mask popcount (h==0)
  __shared__ float rowv[16];       // per-row log(alls)-log(pos)
  __shared__ float rowscale[16];   // per-row 1/Z
  __shared__ float rowc[16];
  const int tid = threadIdx.x;
  const int lane = tid & 63;
  const int wv = tid >> 6;
  const int i0 = blockIdx.x * 16;
  const int bh = blockIdx.y;
  const int b = bh >> 3, h = bh & 7;

  const int lr = lane & 15;  // q-row within tile
  const int lk = lane >> 4;  // k-slot group / j-subgroup

  // Q fragment as B-operand: rows i0+lr, k-slots lk*8 (+32)
  const long qoff = (long)((bh << 10) + i0 + lr) * DHD + lk * 8;
  const bf16x8 q0 = *reinterpret_cast<const bf16x8*>(&Qb[qoff]);
  const bf16x8 q1 = *reinterpret_cast<const bf16x8*>(&Qb[qoff + 32]);
  const short* Kbase = &Kb[(long)(bh << 10) * DHD];
  const float* mrow = mask + ((long)b << 20) + ((long)(i0 + lr) << 10);  // per-lane q-row
  const float* knr = kn + (bh << 10);
  const float inv_qt = qn[(bh << 10) + i0 + lr];  // 1/(||q||*TEMP), per-lane
  const float mlb = kms[bh] / inv_qt;             // ||q||*kmax*SCALE >= max logit
  const float argM = LNEG * SCALE - mlb;

  float Z = 0.f, alls = 0.f, pos = 0.f, cntf = 0.f;
  // ---- fused phase 1+2: per 16-j tile: 2 MFMA -> softmax elems -> LDS ----
#pragma unroll
  for (int jt = 0; jt < 16; ++jt) {
    const int j0 = wv * 256 + jt * 16;
    const long koff = (long)(j0 + lr) * DHD + lk * 8;
    const bf16x8 k0 = *reinterpret_cast<const bf16x8*>(&Kbase[koff]);
    const bf16x8 k1 = *reinterpret_cast<const bf16x8*>(&Kbase[koff + 32]);
    f32x4 acc = {0.f, 0.f, 0.f, 0.f};
    acc = __builtin_amdgcn_mfma_f32_16x16x32_bf16(k0, q0, acc, 0, 0, 0);
    acc = __builtin_amdgcn_mfma_f32_16x16x32_bf16(k1, q1, acc, 0, 0, 0);
    // lane now holds scores[q=i0+lr][j = j0+lk*4+e], e=0..3
    const int jl = j0 + lk * 4;
    const f32x4 mv = *reinterpret_cast<const f32x4*>(&mrow[jl]);
    const f32x4 kv = *reinterpret_cast<const f32x4*>(&knr[jl]);
    bf16x4 p;
#pragma unroll
    for (int e = 0; e < 4; ++e) {
      const float s = acc[e];
      const bool mset = (mv[e] != 0.0f);
      const float ev = __expf(mset ? (s * SCALE - mlb) : argM);  // <= 1
      const float ec = __expf(__builtin_fmaf(s * inv_qt, kv[e], -1.0f / TEMPP));
      Z += ev;
      alls += ec;
      pos += mset ? ec : 0.0f;
      cntf += mset ? 1.0f : 0.0f;
      p[e] = f2bf(ev);
    }
    *reinterpret_cast<bf16x4*>(sp(S, lr, jl)) = p;  // 8B vector write
  }
  // reduce over lk groups (lanes differing in bits 4,5)
  Z += __shfl_xor(Z, 16, 64);    Z += __shfl_xor(Z, 32, 64);
  alls += __shfl_xor(alls, 16, 64); alls += __shfl_xor(alls, 32, 64);
  pos += __shfl_xor(pos, 16, 64);  pos += __shfl_xor(pos, 32, 64);
  if (lk == 0) { red[wv][lr][0] = Z; red[wv][lr][1] = alls; red[wv][lr][2] = pos; }
  if (h == 0) {
    cntf += __shfl_xor(cntf, 16, 64); cntf += __shfl_xor(cntf, 32, 64);
    if (lk == 0) redc[wv][lr] = cntf;
  }
  __syncthreads();

  // ---- per-row totals ----
  const int r = tid >> 4, sub = tid & 15;
  if (sub == 0) {
    const float Zt = red[0][r][0] + red[1][r][0] + red[2][r][0] + red[3][r][0];
    const float at = red[0][r][1] + red[1][r][1] + red[2][r][1] + red[3][r][1];
    const float pt = red[0][r][2] + red[1][r][2] + red[2][r][2] + red[3][r][2];
    rowscale[r] = 1.0f / Zt;
    rowv[r] = __logf(at) - __logf(pt);
    if (h == 0) rowc[r] = redc[0][r] + redc[1][r] + redc[2][r] + redc[3][r];
  }
  __syncthreads();

  // ---- attn write (read ev from LDS, scale, f32 store; drains under PV) ----
  const float rZ = rowscale[r];
  float* arow = attn + ((long)bh << 20) + ((long)(i0 + r) << 10);
#pragma unroll
  for (int k = 0; k < 8; ++k) {
    const int c0 = sub * 8 + k * 128;
    const bf16x8 sv = *reinterpret_cast<const bf16x8*>(sp(S, r, c0));
    f32x4 o0, o1;
#pragma unroll
    for (int e = 0; e < 4; ++e) {
      o0[e] = bf2f(sv[e]) * rZ;
      o1[e] = bf2f(sv[4 + e]) * rZ;
    }
    *reinterpret_cast<f32x4*>(&arow[c0]) = o0;
    *reinterpret_cast<f32x4*>(&arow[c0 + 4]) = o1;
  }
  if (tid == 0) {
    float s = 0.f;
#pragma unroll
    for (int i = 0; i < 16; ++i) s += rowv[i];
    partial[bh * 64 + blockIdx.x] = s;
    if (h == 0) {
      float c = 0.f;
#pragma unroll
      for (int i = 0; i < 16; ++i) c += rowc[i];
      partial2[b * 64 + blockIdx.x] = c - 16.0f;  // diag always 1
    }
  }

  // ---- PV on unnormalized ev; scale by 1/Z in epilogue ----
  f32x4 acc2 = {0.f, 0.f, 0.f, 0.f};
  const short* vrow = &VbT[(long)(bh * DHD + wv * 16 + lr) << 10];
#pragma unroll 8
  for (int k0 = 0; k0 < 32; ++k0) {
    const bf16x8 a = *reinterpret_cast<const bf16x8*>(sp(S, lr, k0 * 32 + lk * 8));
    const bf16x8 bb = *reinterpret_cast<const bf16x8*>(&vrow[k0 * 32 + lk * 8]);
    acc2 = __builtin_amdgcn_mfma_f32_16x16x32_bf16(a, bb, acc2, 0, 0, 0);
  }
#pragma unroll
  for (int i = 0; i < 4; ++i) {
    const int row = lk * 4 + i;
    const float o = acc2[i] * rowscale[row];
    AVb[((long)((b << 10) + i0 + row) << 9) + h * DHD + wv * 16 + lr] = f2bf(o);
  }
}

// ---------------------------------------------------------------------------
// K4: out = av @ Wo.T + bo (f32 out). grid (64, 8).
// ---------------------------------------------------------------------------
__global__ __launch_bounds__(256) void k_outproj(const short* __restrict__ AVb,
                                                 const float* __restrict__ Wo,
                                                 const float* __restrict__ bo,
                                                 float* __restrict__ out) {
  __shared__ __align__(16) short As[64][40];
  __shared__ __align__(16) short Bs[64][40];
  const int tid = threadIdx.x;
  const int lane = tid & 63, wv = tid >> 6;
  const int m0 = blockIdx.x * 64, o0 = blockIdx.y * 64;
  const f32x4 zero4 = {0.f, 0.f, 0.f, 0.f};
  f32x4 acc[4] = {zero4, zero4, zero4, zero4};
  const int ar = tid >> 2, ac = (tid & 3) * 8;
  const int br2 = tid >> 3, bc4 = (tid & 7) * 4;

  for (int ks = 0; ks < 16; ++ks) {
    const int k0 = ks * 32;
    __syncthreads();
    *reinterpret_cast<bf16x8*>(&As[ar][ac]) =
        *reinterpret_cast<const bf16x8*>(&AVb[((long)(m0 + ar) << 9) + k0 + ac]);
#pragma unroll
    for (int t = 0; t < 2; ++t) {
      const int rr = br2 + t * 32;
      const f32x4 vb = *reinterpret_cast<const f32x4*>(&Wo[(o0 + rr) * DIMD + k0 + bc4]);
      bf16x4 pbv;
#pragma unroll
      for (int i2 = 0; i2 < 4; ++i2) pbv[i2] = f2bf(vb[i2]);
      *reinterpret_cast<bf16x4*>(&Bs[rr][bc4]) = pbv;
    }
    __syncthreads();
    const int kk = (lane >> 4) * 8;
    const bf16x8 a = *reinterpret_cast<const bf16x8*>(&As[wv * 16 + (lane & 15)][kk]);
#pragma unroll
    for (int n = 0; n < 4; ++n) {
      const bf16x8 b = *reinterpret_cast<const bf16x8*>(&Bs[n * 16 + (lane & 15)][kk]);
      acc[n] = __builtin_amdgcn_mfma_f32_16x16x32_bf16(a, b, acc[n], 0, 0, 0);
    }
  }
  const int rbase = m0 + wv * 16 + ((lane >> 4) << 2);
#pragma unroll
  for (int i = 0; i < 4; ++i) {
#pragma unroll
    for (int n = 0; n < 4; ++n) {
      const int o = o0 + n * 16 + (lane & 15);
      out[((long)(rbase + i) << 9) + o] = acc[n][i] + bo[o];
    }
  }
}

// ---------------------------------------------------------------------------
// K5: finalize dcl: reduce 2048 clustering partials + 256 regular partials
// ---------------------------------------------------------------------------
__global__ __launch_bounds__(256) void k_finalize(const float* __restrict__ partial,
                                                  const float* __restrict__ partial2,
                                                  float* __restrict__ dcl) {
  const int tid = threadIdx.x;
  float s = 0.f;
#pragma unroll
  for (int t = 0; t < 8; ++t) s += partial[tid + t * 256];
  float s2 = partial2[tid];
  s = wave_sum(s);
  s2 = wave_sum(s2);
  __shared__ float red[4], red2[4];
  if ((tid & 63) == 0) { red[tid >> 6] = s; red2[tid >> 6] = s2; }
  __syncthreads();
  if (tid == 0) {
    const float cl = red[0] + red[1] + red[2] + red[3];
    const float rg = red2[0] + red2[1] + red2[2] + red2[3];
    *dcl = cl / (float)(NB * NH * NN) + KREG * rg / ((float)NN * (float)(NN - 1)) / (float)NB;
  }
}

extern "C" void kernel_launch(void* const* d_in, const int* in_sizes, int n_in,
                              void* d_out, int out_size, void* d_ws, size_t ws_size,
                              hipStream_t stream) {
  const float* x = (const float*)d_in[0];
  const float* mask = (const float*)d_in[1];
  const float* Wq = (const float*)d_in[2];
  const float* bq = (const float*)d_in[3];
  const float* Wk = (const float*)d_in[4];
  const float* bk = (const float*)d_in[5];
  const float* Wv = (const float*)d_in[6];
  const float* bv = (const float*)d_in[7];
  const float* Wo = (const float*)d_in[8];
  const float* bo = (const float*)d_in[9];

  float* out = (float*)d_out;
  float* attn = out + (size_t)NB * NN * DIMD;
  float* dcl = attn + (size_t)NB * NH * NN * NN;

  char* ws = (char*)d_ws;
  short* Qb = (short*)(ws);
  short* Kb = (short*)(ws + ((size_t)4 << 20));
  short* Vb = (short*)(ws + ((size_t)8 << 20));
  short* VbT = (short*)(ws + ((size_t)12 << 20));
  short* AVb = (short*)(ws + ((size_t)16 << 20));
  float* qn = (float*)(ws + ((size_t)20 << 20));
  float* kn = (float*)(ws + ((size_t)20 << 20) + (1 << 18));
  float* kms = (float*)(ws + ((size_t)20 << 20) + (2 << 18));       // 32 f32
  float* partial = (float*)(ws + ((size_t)20 << 20) + (3 << 18));   // 2048 f32
  float* partial2 = (float*)(ws + ((size_t)20 << 20) + (4 << 18));  // 256 f32

  k_qkv<<<dim3(64, 24), 256, 0, stream>>>(x, Wq, bq, Wk, bk, Wv, bv, Qb, Kb, Vb, qn, kn);
  k_vtrans<<<dim3(16, 32), 256, 0, stream>>>(Vb, VbT);
  k_kmax<<<dim3(32), 256, 0, stream>>>(kn, kms);
  k_attn<<<dim3(64, 32), 256, 0, stream>>>(Qb, Kb, VbT, mask, qn, kn, kms, attn, AVb,
                                           partial, partial2);
  k_outproj<<<dim3(64, 8), 256, 0, stream>>>(AVb, Wo, bo, out);
  k_finalize<<<1, 256, 0, stream>>>(partial, partial2, dcl);
}